// Round 1
// baseline (258.547 us; speedup 1.0000x reference)
//
#include <hip/hip_runtime.h>

#define TT 2048
#define BB 8192
#define NCHUNK 8
#define SS (TT / NCHUNK)   // 256 outputs per chunk
#define WW 256             // warmup steps (state influence decays ~prod(z) -> negligible)

struct GruConsts {
  float axs[4], bs[4], u0s[4], u1s[4];     // r,z gates, prescaled by -log2(e)
  float axn[2], bxn[2], an0[2], an1[2], bhn[2]; // n gate, prescaled by 2*log2(e)
};

__device__ __forceinline__ float rcpf_(float v)  { return __builtin_amdgcn_rcpf(v); }
__device__ __forceinline__ float exp2f_(float v) { return __builtin_amdgcn_exp2f(v); }

// One GRU step. Gate args come pre-scaled so sigmoid(u) = rcp(1+exp2(u_scaled))
// and tanh(v) = 1 - 2*rcp(1+exp2(v_scaled)).
__device__ __forceinline__ void gru_step(const GruConsts& K, float xs, float& h0, float& h1)
{
  float u0 = fmaf(K.u1s[0], h1, fmaf(K.u0s[0], h0, fmaf(K.axs[0], xs, K.bs[0])));
  float u1 = fmaf(K.u1s[1], h1, fmaf(K.u0s[1], h0, fmaf(K.axs[1], xs, K.bs[1])));
  float u2 = fmaf(K.u1s[2], h1, fmaf(K.u0s[2], h0, fmaf(K.axs[2], xs, K.bs[2])));
  float u3 = fmaf(K.u1s[3], h1, fmaf(K.u0s[3], h0, fmaf(K.axs[3], xs, K.bs[3])));
  float r0 = rcpf_(1.f + exp2f_(u0));
  float r1 = rcpf_(1.f + exp2f_(u1));
  float z0 = rcpf_(1.f + exp2f_(u2));
  float z1 = rcpf_(1.f + exp2f_(u3));
  float gxn0 = fmaf(K.axn[0], xs, K.bxn[0]);
  float gxn1 = fmaf(K.axn[1], xs, K.bxn[1]);
  float ghn0 = fmaf(K.an1[0], h1, fmaf(K.an0[0], h0, K.bhn[0]));
  float ghn1 = fmaf(K.an1[1], h1, fmaf(K.an0[1], h0, K.bhn[1]));
  float n0 = fmaf(-2.f, rcpf_(1.f + exp2f_(fmaf(r0, ghn0, gxn0))), 1.f);
  float n1 = fmaf(-2.f, rcpf_(1.f + exp2f_(fmaf(r1, ghn1, gxn1))), 1.f);
  h0 = fmaf(z0, h0 - n0, n0);   // (1-z)*n + z*h
  h1 = fmaf(z1, h1 - n1, n1);
}

__device__ __forceinline__ float2 epilogue(float h0, float h1)
{
  const float L1 = -1.4426950408889634f; // -log2(e)
  const float L2 =  2.8853900817779268f; //  2*log2(e)
  float t0 = fmaf(-2.f, rcpf_(1.f + exp2f_(L2 * h0)), 1.f); // tanh(h0)
  float t1 = fmaf(-2.f, rcpf_(1.f + exp2f_(L2 * h1)), 1.f); // tanh(h1)
  float alpha = 2.5f * exp2f_(1.4426950408889634f * t0);    // 2.5*exp(t0)
  float beta  = 4.f  * rcpf_(1.f + exp2f_(L1 * t1));        // 4*sigmoid(t1)
  return make_float2(alpha, beta);
}

__global__ __launch_bounds__(256)
void WTTERNN_gru(const float* __restrict__ xg, const float* __restrict__ wih,
                 const float* __restrict__ whh, const float* __restrict__ bih,
                 const float* __restrict__ bhh, float* __restrict__ out)
{
  const float L1 = -1.4426950408889634f;
  const float L2 =  2.8853900817779268f;
  GruConsts K;
  // Gate order in the 3H=6 dim: [r0,r1, z0,z1, n0,n1]. w_hh is row-major (6,2).
  #pragma unroll
  for (int g = 0; g < 4; ++g) {
    K.axs[g] = L1 * wih[g];
    K.bs [g] = L1 * (bih[g] + bhh[g]);
    K.u0s[g] = L1 * whh[2*g];
    K.u1s[g] = L1 * whh[2*g + 1];
  }
  #pragma unroll
  for (int j = 0; j < 2; ++j) {
    K.axn[j] = L2 * wih[4+j];
    K.bxn[j] = L2 * bih[4+j];
    K.an0[j] = L2 * whh[2*(4+j)];
    K.an1[j] = L2 * whh[2*(4+j) + 1];
    K.bhn[j] = L2 * bhh[4+j];
  }

  const int tid = blockIdx.x * blockDim.x + threadIdx.x; // 65536 threads
  const int b = tid & (BB - 1);        // batch chain
  const int c = tid >> 13;             // chunk id 0..7
  const float* xp = xg + (size_t)b * TT;
  float4* out4 = (float4*)out;
  const size_t obase = ((size_t)b * TT) >> 1; // float4 index of row start

  float h0 = 0.f, h1 = 0.f;
  const int tout = c * SS;
  int t = tout - WW;
  if (t < 0) t = 0;

  // Warmup: recurrence only, no epilogue, outputs discarded.
  for (; t < tout; t += 4) {
    const float4 xv = *reinterpret_cast<const float4*>(xp + t);
    gru_step(K, xv.x, h0, h1);
    gru_step(K, xv.y, h0, h1);
    gru_step(K, xv.z, h0, h1);
    gru_step(K, xv.w, h0, h1);
  }
  // Output region.
  for (; t < tout + SS; t += 4) {
    const float4 xv = *reinterpret_cast<const float4*>(xp + t);
    gru_step(K, xv.x, h0, h1); float2 e0 = epilogue(h0, h1);
    gru_step(K, xv.y, h0, h1); float2 e1 = epilogue(h0, h1);
    out4[obase + ((size_t)t >> 1)] = make_float4(e0.x, e0.y, e1.x, e1.y);
    gru_step(K, xv.z, h0, h1); float2 e2 = epilogue(h0, h1);
    gru_step(K, xv.w, h0, h1); float2 e3 = epilogue(h0, h1);
    out4[obase + ((size_t)t >> 1) + 1] = make_float4(e2.x, e2.y, e3.x, e3.y);
  }
}

extern "C" void kernel_launch(void* const* d_in, const int* in_sizes, int n_in,
                              void* d_out, int out_size, void* d_ws, size_t ws_size,
                              hipStream_t stream)
{
  (void)in_sizes; (void)n_in; (void)out_size; (void)d_ws; (void)ws_size;
  const float* x   = (const float*)d_in[0];
  const float* wih = (const float*)d_in[1];
  const float* whh = (const float*)d_in[2];
  const float* bih = (const float*)d_in[3];
  const float* bhh = (const float*)d_in[4];
  float* out = (float*)d_out;

  dim3 grid((BB * NCHUNK) / 256);
  dim3 block(256);
  hipLaunchKernelGGL(WTTERNN_gru, grid, block, 0, stream, x, wih, whh, bih, bhh, out);
}